// Round 7
// baseline (1087.799 us; speedup 1.0000x reference)
//
#include <hip/hip_runtime.h>

typedef __attribute__((ext_vector_type(8))) short short8;
typedef __attribute__((ext_vector_type(8))) int int8v;
typedef __attribute__((ext_vector_type(16))) float floatx16;
typedef __attribute__((ext_vector_type(4))) unsigned int uint4v;
typedef unsigned short ushort_t;
typedef unsigned int uint_t;
typedef unsigned char uchar_t;

#define NA   256
#define CIN  128
#define HFD  320
#define FMPX (HFD*HFD)
#define IMGD 1280

// ws layout (bytes):
//   [0, 1MB)            logits f32 (NA*1024)
//   [1MB, +294912)      w1r fp8 [9 tap][256 oc][128 cin], scaled x64
//   [+294912, +16384)   w2r bf16 [32 krow][256 oc]
//   [+16384, +1024)     cnt int32 [256]
//   [2MB, +13107200)    fmT fp8 [320 y][320 x][128 c]
#define W1R_BYTE_OFF (1u<<20)
#define W2R_BYTE_OFF ((1u<<20) + 9*256*128)
#define CNT_BYTE_OFF ((1u<<20) + 9*256*128 + 32*256*2)
#define FMT_BYTE_OFF (2u<<20)

#define SAPL 5440                 // A sub-plane bytes: 10*34 cells * 16
#define SA_BYTES (4*SAPL)         // 21760
#define PSTR_H 4112               // bytes per oc-octet plane of s_h (8*32*16 + 16 pad)
#define SH_BYTES (8*PSTR_H)       // 32896
#define SMEM_BYTES 32896          // max(SA, SH)

union V32 { int8v v; uint4v q[2]; };

__device__ __forceinline__ ushort_t f2bf(float v) {
    uint_t u = __float_as_uint(v);
    return (ushort_t)((u + 0x8000u) >> 16);
}
__device__ __forceinline__ uchar_t f2fp8(float v) {
    int r = __builtin_amdgcn_cvt_pk_fp8_f32(v, 0.0f, 0, false);
    return (uchar_t)(r & 0xff);
}

// One prep kernel: fm transpose->fp8 channels-last, W1 repack (x64 fp8), W2 repack (bf16),
// logits/out/cnt zeroing.
__global__ __launch_bounds__(256) void prep_kernel(
    const float* __restrict__ fm, const float* __restrict__ W1, const float* __restrict__ W2,
    float* __restrict__ logits, float* __restrict__ out,
    uchar_t* __restrict__ w1r, ushort_t* __restrict__ w2r,
    int* __restrict__ cnt, uchar_t* __restrict__ fmT)
{
    const int b = blockIdx.x, t = threadIdx.x;
    if (b < 3200) {
        if (b < 1024) logits[b * 256 + t] = 0.0f;
        __shared__ uchar_t s[32 * 144];
        const int y = b / 10, x0b = (b % 10) * 32;
        #pragma unroll
        for (int i = 0; i < 16; ++i) {
            int e = t + 256 * i;
            int c = e >> 5, xo = e & 31;
            s[xo * 144 + c] = f2fp8(fm[(size_t)c * FMPX + y * HFD + x0b + xo]);
        }
        __syncthreads();
        int xo = t >> 3, cg = t & 7;
        uint4v v = *(const uint4v*)&s[xo * 144 + cg * 16];
        *(uint4v*)&fmT[((size_t)(y * HFD + x0b + xo)) * 128 + cg * 16] = v;
    } else if (b < 3328) {
        int e = (b - 3200) * 256 + t;
        int oc = e >> 7, cin = e & 127;
        #pragma unroll
        for (int tap = 0; tap < 9; ++tap)
            w1r[(tap * 256 + oc) * 128 + cin] = f2fp8(W1[(oc * 128 + cin) * 9 + tap] * 64.0f);
    } else {
        #pragma unroll
        for (int i = 0; i < 32; ++i) {
            int e = i * 256 + t;
            int nrow = e >> 8, oc = e & 255;
            w2r[nrow * 256 + oc] = f2bf(nrow < 9 ? W2[oc * 9 + nrow] : 0.0f);
        }
        cnt[t] = 0;
        if (t == 0) out[0] = 0.0f;
    }
}

// Block = (anchor, 8-row quarter, 64-oc group); grid 4096, XCD-swizzled (16 blocks/anchor on one XCD).
// Wave w owns out-rows {2w,2w+1} x 64 oc (2 n-tiles) on mfma_scale 32x32x64 fp8 (unity E8M0=127).
// A staged in LDS sub-plane layout [sub 4][10 pr][34 pc][16B] (reads/writes lane-16B contiguous);
// B read straight from global w1r (4KB slab per (kx,ky) -> L1-hot across the 4 waves).
// acc = 64 VGPR -> target 16 waves/CU; LDS ~33.4KB -> 4 blocks/CU.
// Epilogue: relu(h/64+b1) -> s_h (union) -> v_tap = h @ W2^T (bf16 MFMA) -> scatter via s_log ->
// global logits atomics -> last-of-16 block per anchor computes BCE inline (agent-scope sync).
__global__ __launch_bounds__(256, 4) void conv_mfma_kernel(
    const int* __restrict__ anchors, const uchar_t* __restrict__ fmT,
    const uchar_t* __restrict__ w1r, const ushort_t* __restrict__ w2r,
    const float* __restrict__ b1, float* __restrict__ logits,
    int* __restrict__ cnt, const int* __restrict__ seg,
    const int* __restrict__ labels, const int* __restrict__ base_classes,
    const float* __restrict__ b2, float* __restrict__ out)
{
    const int id  = blockIdx.x;
    const int xcd = id & 7, sid = id >> 3;
    const int n   = xcd * 32 + (sid >> 4);
    const int rem = sid & 15;
    const int q   = rem >> 2;
    const int g   = rem & 3;

    const int t    = threadIdx.x;
    const int w    = t >> 6;
    const int lane = t & 63;
    const int l31  = lane & 31;
    const int kh   = lane >> 5;

    const int x0 = anchors[n * 4 + 0];
    const int y0 = anchors[n * 4 + 2];
    const int r0 = q * 8;

    __shared__ __align__(16) char smem[SMEM_BYTES];   // s_a (21760) union s_h (32896)
    __shared__ float s_log[10 * 32];
    __shared__ float sred[4];
    __shared__ int s_last;

    // zero s_a once (pad rows/cols stay zero; real cells overwritten per chunk)
    for (int i = t; i < SA_BYTES / 4; i += 256) ((uint_t*)smem)[i] = 0u;

    floatx16 acc[2][2];
    #pragma unroll
    for (int mt = 0; mt < 2; ++mt)
        #pragma unroll
        for (int nt = 0; nt < 2; ++nt)
            #pragma unroll
            for (int r = 0; r < 16; ++r) acc[mt][nt][r] = 0.0f;

    for (int c = 0; c < 2; ++c) {
        const int cb = c * 64;
        __syncthreads();   // c0: zeros visible; c1: all waves done reading chunk0
        // ---- stage A: 10 rows x 32 cols x 4 subs = 1280 units, exactly 5/thread ----
        #pragma unroll
        for (int j = 0; j < 5; ++j) {
            int u = t + 256 * j;
            int sub = u & 3, cell = u >> 2;
            int col = cell & 31, pr = cell >> 5;
            int cr = r0 + pr - 1;
            if ((unsigned)cr < 32u) {
                uint4v v = *(const uint4v*)&fmT[((size_t)((y0 + cr) * HFD + x0 + col)) * 128 + cb + sub * 16];
                *(uint4v*)(smem + sub * SAPL + (pr * 34 + col + 1) * 16) = v;
            }
        }
        __syncthreads();
        // ---- MFMA: per kx cache 4 A-row-frags (ky-shared); B from global per (kx,ky) ----
        #pragma unroll
        for (int kx = 0; kx < 3; ++kx) {
            V32 a8[4];
            #pragma unroll
            for (int idx = 0; idx < 4; ++idx) {
                int cell = (2 * w + idx) * 34 + l31 + kx;
                a8[idx].q[0] = *(const uint4v*)(smem + (2 * kh)     * SAPL + cell * 16);
                a8[idx].q[1] = *(const uint4v*)(smem + (2 * kh + 1) * SAPL + cell * 16);
            }
            #pragma unroll
            for (int ky = 0; ky < 3; ++ky) {
                const int tap = ky * 3 + kx;
                V32 b8[2];
                #pragma unroll
                for (int nt = 0; nt < 2; ++nt) {
                    const uchar_t* bp = w1r + (size_t)((tap * 256 + g * 64 + nt * 32 + l31) * 128) + cb + kh * 32;
                    b8[nt].q[0] = *(const uint4v*)bp;
                    b8[nt].q[1] = *(const uint4v*)(bp + 16);
                }
                #pragma unroll
                for (int mt = 0; mt < 2; ++mt) {
                    acc[mt][0] = __builtin_amdgcn_mfma_scale_f32_32x32x64_f8f6f4(
                        a8[mt + ky].v, b8[0].v, acc[mt][0], 0, 0, 0, 127, 0, 127);
                    acc[mt][1] = __builtin_amdgcn_mfma_scale_f32_32x32x64_f8f6f4(
                        a8[mt + ky].v, b8[1].v, acc[mt][1], 0, 0, 0, 127, 0, 127);
                }
            }
        }
    }

    // ---- epilogue: h = acc/64 + b1, relu -> s_h (union with s_a) ----
    __syncthreads();
    #pragma unroll
    for (int nt = 0; nt < 2; ++nt) {
        float bias = b1[g * 64 + nt * 32 + l31];
        int plane = nt * 4 + (l31 >> 3);
        #pragma unroll
        for (int mt = 0; mt < 2; ++mt) {
            int lr = 2 * w + mt;
            #pragma unroll
            for (int reg = 0; reg < 16; ++reg) {
                int col = (reg & 3) + 8 * (reg >> 2) + 4 * kh;   // C: m = crop col
                float hv = fmaxf(fmaf(acc[mt][nt][reg], 0.015625f, bias), 0.0f);
                *(ushort_t*)(smem + plane * PSTR_H + ((lr * 32 + col) * 8 + (l31 & 7)) * 2) = f2bf(hv);
            }
        }
    }
    __syncthreads();

    // ---- v_tap = h @ W2^T (bf16, K=64 oc over 4 x K16) ----
    floatx16 vacc[2];
    #pragma unroll
    for (int mt = 0; mt < 2; ++mt)
        #pragma unroll
        for (int r = 0; r < 16; ++r) vacc[mt][r] = 0.0f;
    #pragma unroll
    for (int ks = 0; ks < 4; ++ks) {
        short8 bw = *(const short8*)&w2r[l31 * 256 + g * 64 + ks * 16 + kh * 8];
        #pragma unroll
        for (int mt = 0; mt < 2; ++mt) {
            short8 ah = *(const short8*)(smem + (ks * 2 + kh) * PSTR_H + ((2 * w + mt) * 32 + l31) * 16);
            vacc[mt] = __builtin_amdgcn_mfma_f32_32x32x16_bf16(ah, bw, vacc[mt], 0, 0, 0);
        }
    }

    // ---- scatter v_tap into 10x32 tile, then global atomics ----
    __syncthreads();
    for (int i = t; i < 10 * 32; i += 256) s_log[i] = 0.0f;
    __syncthreads();
    if (l31 < 9) {
        int ky = l31 / 3, kx = l31 - ky * 3;
        #pragma unroll
        for (int mt = 0; mt < 2; ++mt) {
            int outr = 2 * w + mt + 2 - ky;       // tile row; R = r0 + outr - 1
            #pragma unroll
            for (int reg = 0; reg < 16; ++reg) {
                int col  = (reg & 3) + 8 * (reg >> 2) + 4 * kh;
                int outc = col + 1 - kx;
                if (outc >= 0 && outc < 32)
                    atomicAdd(&s_log[outr * 32 + outc], vacc[mt][reg]);
            }
        }
    }
    __syncthreads();
    for (int i = t; i < 10 * 32; i += 256) {
        int outr = i >> 5, outc = i & 31;
        int R = r0 + outr - 1;
        if ((unsigned)R < 32u)
            atomicAdd(&logits[n * 1024 + R * 32 + outc], s_log[i]);
    }

    // ---- last-of-16 block per anchor: fused BCE reduction ----
    __threadfence();
    __syncthreads();
    if (t == 0) {
        int old = __hip_atomic_fetch_add(&cnt[n], 1, __ATOMIC_ACQ_REL, __HIP_MEMORY_SCOPE_AGENT);
        s_last = (old == 15) ? 1 : 0;
    }
    __syncthreads();
    if (s_last) {
        const int tgt_cls = base_classes[labels[n]];
        const float bias2 = b2[0];
        float lsum = 0.0f;
        #pragma unroll
        for (int r = 0; r < 4; ++r) {
            int p = t + r * 256;
            int i = p >> 5, j = p & 31;
            float l = __hip_atomic_load(&logits[n * 1024 + p], __ATOMIC_RELAXED,
                                        __HIP_MEMORY_SCOPE_AGENT) + bias2;
            int sv = seg[(size_t)(4 * (y0 + i)) * IMGD + 4 * (x0 + j)];
            float tgt = (sv == tgt_cls) ? 1.0f : 0.0f;
            lsum += fmaxf(l, 0.0f) - l * tgt + log1pf(expf(-fabsf(l)));
        }
        #pragma unroll
        for (int off = 32; off > 0; off >>= 1) lsum += __shfl_down(lsum, off, 64);
        if ((t & 63) == 0) sred[t >> 6] = lsum;
        __syncthreads();
        if (t == 0) {
            float tot = sred[0] + sred[1] + sred[2] + sred[3];
            const float scale = 1.0f / (1024.0f * (256.0f + 1e-10f));
            atomicAdd(out, tot * scale);
        }
    }
}

extern "C" void kernel_launch(void* const* d_in, const int* in_sizes, int n_in,
                              void* d_out, int out_size, void* d_ws, size_t ws_size,
                              hipStream_t stream) {
    const float* fm           = (const float*)d_in[0];
    const int*   seg          = (const int*)d_in[1];
    const int*   anchors      = (const int*)d_in[2];
    const int*   labels       = (const int*)d_in[3];
    const int*   base_classes = (const int*)d_in[4];
    const float* W1           = (const float*)d_in[5];
    const float* b1           = (const float*)d_in[6];
    const float* W2           = (const float*)d_in[7];
    const float* b2           = (const float*)d_in[8];
    float* out = (float*)d_out;

    float*    logits = (float*)d_ws;
    uchar_t*  w1r    = (uchar_t*)((char*)d_ws + W1R_BYTE_OFF);
    ushort_t* w2r    = (ushort_t*)((char*)d_ws + W2R_BYTE_OFF);
    int*      cnt    = (int*)((char*)d_ws + CNT_BYTE_OFF);
    uchar_t*  fmT    = (uchar_t*)((char*)d_ws + FMT_BYTE_OFF);

    prep_kernel<<<3329, 256, 0, stream>>>(fm, W1, W2, logits, out, w1r, w2r, cnt, fmT);
    conv_mfma_kernel<<<4096, 256, 0, stream>>>(anchors, fmT, w1r, w2r, b1, logits,
                                               cnt, seg, labels, base_classes, b2, out);
}

// Round 8
// 602.739 us; speedup vs baseline: 1.8048x; 1.8048x over previous
//
#include <hip/hip_runtime.h>

typedef __attribute__((ext_vector_type(8))) short short8;
typedef __attribute__((ext_vector_type(8))) int int8v;
typedef __attribute__((ext_vector_type(16))) float floatx16;
typedef __attribute__((ext_vector_type(4))) unsigned int uint4v;
typedef unsigned short ushort_t;
typedef unsigned int uint_t;
typedef unsigned char uchar_t;

#define NA   256
#define CIN  128
#define HFD  320
#define FMPX (HFD*HFD)
#define IMGD 1280

// ws layout (bytes):
//   [0, 1MB)            logits f32 (NA*1024)
//   [1MB, +294912)      w1r fp8 [9 tap][256 oc][128 cin], scaled x64
//   [+294912, +16384)   w2r bf16 [32 krow][256 oc]
//   [+16384, +1024)     cnt int32 [256]
//   [2MB, +13107200)    fmT fp8 [320 y][320 x][128 c]
#define W1R_BYTE_OFF (1u<<20)
#define W2R_BYTE_OFF ((1u<<20) + 9*256*128)
#define CNT_BYTE_OFF ((1u<<20) + 9*256*128 + 32*256*2)
#define FMT_BYTE_OFF (2u<<20)

#define SAPL 5440                 // A sub-plane bytes: 10*34 cells * 16
#define SA_BYTES (4*SAPL)         // 21760
#define PSTR_H 4112               // bytes per oc-octet plane of s_h (8*32*16 + 16 pad)
#define SH_BYTES (8*PSTR_H)       // 32896
#define SMEM_BYTES 32896          // max(SA, SH)

union V32 { int8v v; uint4v q[2]; };

__device__ __forceinline__ ushort_t f2bf(float v) {
    uint_t u = __float_as_uint(v);
    return (ushort_t)((u + 0x8000u) >> 16);
}
__device__ __forceinline__ uchar_t f2fp8(float v) {
    int r = __builtin_amdgcn_cvt_pk_fp8_f32(v, 0.0f, 0, false);
    return (uchar_t)(r & 0xff);
}

// One prep kernel: fm transpose->fp8 channels-last, W1 repack (x64 fp8), W2 repack (bf16),
// logits/out/cnt zeroing.
__global__ __launch_bounds__(256) void prep_kernel(
    const float* __restrict__ fm, const float* __restrict__ W1, const float* __restrict__ W2,
    float* __restrict__ logits, float* __restrict__ out,
    uchar_t* __restrict__ w1r, ushort_t* __restrict__ w2r,
    int* __restrict__ cnt, uchar_t* __restrict__ fmT)
{
    const int b = blockIdx.x, t = threadIdx.x;
    if (b < 3200) {
        if (b < 1024) logits[b * 256 + t] = 0.0f;
        __shared__ uchar_t s[32 * 144];
        const int y = b / 10, x0b = (b % 10) * 32;
        #pragma unroll
        for (int i = 0; i < 16; ++i) {
            int e = t + 256 * i;
            int c = e >> 5, xo = e & 31;
            s[xo * 144 + c] = f2fp8(fm[(size_t)c * FMPX + y * HFD + x0b + xo]);
        }
        __syncthreads();
        int xo = t >> 3, cg = t & 7;
        uint4v v = *(const uint4v*)&s[xo * 144 + cg * 16];
        *(uint4v*)&fmT[((size_t)(y * HFD + x0b + xo)) * 128 + cg * 16] = v;
    } else if (b < 3328) {
        int e = (b - 3200) * 256 + t;
        int oc = e >> 7, cin = e & 127;
        #pragma unroll
        for (int tap = 0; tap < 9; ++tap)
            w1r[(tap * 256 + oc) * 128 + cin] = f2fp8(W1[(oc * 128 + cin) * 9 + tap] * 64.0f);
    } else {
        #pragma unroll
        for (int i = 0; i < 32; ++i) {
            int e = i * 256 + t;
            int nrow = e >> 8, oc = e & 255;
            w2r[nrow * 256 + oc] = f2bf(nrow < 9 ? W2[oc * 9 + nrow] : 0.0f);
        }
        cnt[t] = 0;
        if (t == 0) out[0] = 0.0f;
    }
}

// Block = (anchor, 8-row quarter, 64-oc group); grid 4096, XCD-swizzled.
// Wave w owns out-rows {2w,2w+1} x 64 oc (2 n-tiles) on mfma_scale 32x32x64 fp8 (unity E8M0=127).
// A staged in LDS sub-plane layout [sub 4][10 pr][34 pc][16B]; B straight from global (L1-hot).
// launch_bounds (256,2): empirically caps VGPR at 128 -- (256,4) capped at 64 and spilled
// catastrophically (R7: 881 MB scratch writes). Natural usage ~110 -> 4 waves/SIMD, 4 blocks/CU.
// Epilogue: relu(h/64+b1) -> s_h (union) -> v_tap = h @ W2^T (bf16) -> scatter -> logits atomics
// -> last-of-16 block per anchor computes BCE inline (agent-scope).
__global__ __launch_bounds__(256, 2) void conv_mfma_kernel(
    const int* __restrict__ anchors, const uchar_t* __restrict__ fmT,
    const uchar_t* __restrict__ w1r, const ushort_t* __restrict__ w2r,
    const float* __restrict__ b1, float* __restrict__ logits,
    int* __restrict__ cnt, const int* __restrict__ seg,
    const int* __restrict__ labels, const int* __restrict__ base_classes,
    const float* __restrict__ b2, float* __restrict__ out)
{
    const int id  = blockIdx.x;
    const int xcd = id & 7, sid = id >> 3;
    const int n   = xcd * 32 + (sid >> 4);
    const int rem = sid & 15;
    const int q   = rem >> 2;
    const int g   = rem & 3;

    const int t    = threadIdx.x;
    const int w    = t >> 6;
    const int lane = t & 63;
    const int l31  = lane & 31;
    const int kh   = lane >> 5;

    const int x0 = anchors[n * 4 + 0];
    const int y0 = anchors[n * 4 + 2];
    const int r0 = q * 8;

    __shared__ __align__(16) char smem[SMEM_BYTES];   // s_a (21760) union s_h (32896)
    __shared__ float s_log[10 * 32];
    __shared__ float sred[4];
    __shared__ int s_last;

    // zero s_a once (pad rows/cols stay zero; real cells overwritten per chunk)
    for (int i = t; i < SA_BYTES / 4; i += 256) ((uint_t*)smem)[i] = 0u;

    floatx16 acc[2][2];
    #pragma unroll
    for (int mt = 0; mt < 2; ++mt)
        #pragma unroll
        for (int nt = 0; nt < 2; ++nt)
            #pragma unroll
            for (int r = 0; r < 16; ++r) acc[mt][nt][r] = 0.0f;

    for (int c = 0; c < 2; ++c) {
        const int cb = c * 64;
        __syncthreads();   // c0: zeros visible; c1: all waves done reading chunk0
        // ---- stage A: 10 rows x 32 cols x 4 subs = 1280 units, exactly 5/thread ----
        #pragma unroll
        for (int j = 0; j < 5; ++j) {
            int u = t + 256 * j;
            int sub = u & 3, cell = u >> 2;
            int col = cell & 31, pr = cell >> 5;
            int cr = r0 + pr - 1;
            if ((unsigned)cr < 32u) {
                uint4v v = *(const uint4v*)&fmT[((size_t)((y0 + cr) * HFD + x0 + col)) * 128 + cb + sub * 16];
                *(uint4v*)(smem + sub * SAPL + (pr * 34 + col + 1) * 16) = v;
            }
        }
        __syncthreads();
        // ---- MFMA: per kx cache 4 A-row-frags (ky-shared); B from global per (kx,ky) ----
        #pragma unroll
        for (int kx = 0; kx < 3; ++kx) {
            V32 a8[4];
            #pragma unroll
            for (int idx = 0; idx < 4; ++idx) {
                int cell = (2 * w + idx) * 34 + l31 + kx;
                a8[idx].q[0] = *(const uint4v*)(smem + (2 * kh)     * SAPL + cell * 16);
                a8[idx].q[1] = *(const uint4v*)(smem + (2 * kh + 1) * SAPL + cell * 16);
            }
            #pragma unroll
            for (int ky = 0; ky < 3; ++ky) {
                const int tap = ky * 3 + kx;
                V32 b8[2];
                #pragma unroll
                for (int nt = 0; nt < 2; ++nt) {
                    const uchar_t* bp = w1r + (size_t)((tap * 256 + g * 64 + nt * 32 + l31) * 128) + cb + kh * 32;
                    b8[nt].q[0] = *(const uint4v*)bp;
                    b8[nt].q[1] = *(const uint4v*)(bp + 16);
                }
                #pragma unroll
                for (int mt = 0; mt < 2; ++mt) {
                    acc[mt][0] = __builtin_amdgcn_mfma_scale_f32_32x32x64_f8f6f4(
                        a8[mt + ky].v, b8[0].v, acc[mt][0], 0, 0, 0, 127, 0, 127);
                    acc[mt][1] = __builtin_amdgcn_mfma_scale_f32_32x32x64_f8f6f4(
                        a8[mt + ky].v, b8[1].v, acc[mt][1], 0, 0, 0, 127, 0, 127);
                }
            }
        }
    }

    // ---- epilogue: h = acc/64 + b1, relu -> s_h (union with s_a) ----
    __syncthreads();
    #pragma unroll
    for (int nt = 0; nt < 2; ++nt) {
        float bias = b1[g * 64 + nt * 32 + l31];
        int plane = nt * 4 + (l31 >> 3);
        #pragma unroll
        for (int mt = 0; mt < 2; ++mt) {
            int lr = 2 * w + mt;
            #pragma unroll
            for (int reg = 0; reg < 16; ++reg) {
                int col = (reg & 3) + 8 * (reg >> 2) + 4 * kh;   // C: m = crop col
                float hv = fmaxf(fmaf(acc[mt][nt][reg], 0.015625f, bias), 0.0f);
                *(ushort_t*)(smem + plane * PSTR_H + ((lr * 32 + col) * 8 + (l31 & 7)) * 2) = f2bf(hv);
            }
        }
    }
    __syncthreads();

    // ---- v_tap = h @ W2^T (bf16, K=64 oc over 4 x K16) ----
    floatx16 vacc[2];
    #pragma unroll
    for (int mt = 0; mt < 2; ++mt)
        #pragma unroll
        for (int r = 0; r < 16; ++r) vacc[mt][r] = 0.0f;
    #pragma unroll
    for (int ks = 0; ks < 4; ++ks) {
        short8 bw = *(const short8*)&w2r[l31 * 256 + g * 64 + ks * 16 + kh * 8];
        #pragma unroll
        for (int mt = 0; mt < 2; ++mt) {
            short8 ah = *(const short8*)(smem + (ks * 2 + kh) * PSTR_H + ((2 * w + mt) * 32 + l31) * 16);
            vacc[mt] = __builtin_amdgcn_mfma_f32_32x32x16_bf16(ah, bw, vacc[mt], 0, 0, 0);
        }
    }

    // ---- scatter v_tap into 10x32 tile, then global atomics ----
    __syncthreads();
    for (int i = t; i < 10 * 32; i += 256) s_log[i] = 0.0f;
    __syncthreads();
    if (l31 < 9) {
        int ky = l31 / 3, kx = l31 - ky * 3;
        #pragma unroll
        for (int mt = 0; mt < 2; ++mt) {
            int outr = 2 * w + mt + 2 - ky;       // tile row; R = r0 + outr - 1
            #pragma unroll
            for (int reg = 0; reg < 16; ++reg) {
                int col  = (reg & 3) + 8 * (reg >> 2) + 4 * kh;
                int outc = col + 1 - kx;
                if (outc >= 0 && outc < 32)
                    atomicAdd(&s_log[outr * 32 + outc], vacc[mt][reg]);
            }
        }
    }
    __syncthreads();
    for (int i = t; i < 10 * 32; i += 256) {
        int outr = i >> 5, outc = i & 31;
        int R = r0 + outr - 1;
        if ((unsigned)R < 32u)
            atomicAdd(&logits[n * 1024 + R * 32 + outc], s_log[i]);
    }

    // ---- last-of-16 block per anchor: fused BCE reduction ----
    __threadfence();
    __syncthreads();
    if (t == 0) {
        int old = __hip_atomic_fetch_add(&cnt[n], 1, __ATOMIC_ACQ_REL, __HIP_MEMORY_SCOPE_AGENT);
        s_last = (old == 15) ? 1 : 0;
    }
    __syncthreads();
    if (s_last) {
        const int tgt_cls = base_classes[labels[n]];
        const float bias2 = b2[0];
        float lsum = 0.0f;
        #pragma unroll
        for (int r = 0; r < 4; ++r) {
            int p = t + r * 256;
            int i = p >> 5, j = p & 31;
            float l = __hip_atomic_load(&logits[n * 1024 + p], __ATOMIC_RELAXED,
                                        __HIP_MEMORY_SCOPE_AGENT) + bias2;
            int sv = seg[(size_t)(4 * (y0 + i)) * IMGD + 4 * (x0 + j)];
            float tgt = (sv == tgt_cls) ? 1.0f : 0.0f;
            lsum += fmaxf(l, 0.0f) - l * tgt + log1pf(expf(-fabsf(l)));
        }
        #pragma unroll
        for (int off = 32; off > 0; off >>= 1) lsum += __shfl_down(lsum, off, 64);
        if ((t & 63) == 0) sred[t >> 6] = lsum;
        __syncthreads();
        if (t == 0) {
            float tot = sred[0] + sred[1] + sred[2] + sred[3];
            const float scale = 1.0f / (1024.0f * (256.0f + 1e-10f));
            atomicAdd(out, tot * scale);
        }
    }
}

extern "C" void kernel_launch(void* const* d_in, const int* in_sizes, int n_in,
                              void* d_out, int out_size, void* d_ws, size_t ws_size,
                              hipStream_t stream) {
    const float* fm           = (const float*)d_in[0];
    const int*   seg          = (const int*)d_in[1];
    const int*   anchors      = (const int*)d_in[2];
    const int*   labels       = (const int*)d_in[3];
    const int*   base_classes = (const int*)d_in[4];
    const float* W1           = (const float*)d_in[5];
    const float* b1           = (const float*)d_in[6];
    const float* W2           = (const float*)d_in[7];
    const float* b2           = (const float*)d_in[8];
    float* out = (float*)d_out;

    float*    logits = (float*)d_ws;
    uchar_t*  w1r    = (uchar_t*)((char*)d_ws + W1R_BYTE_OFF);
    ushort_t* w2r    = (ushort_t*)((char*)d_ws + W2R_BYTE_OFF);
    int*      cnt    = (int*)((char*)d_ws + CNT_BYTE_OFF);
    uchar_t*  fmT    = (uchar_t*)((char*)d_ws + FMT_BYTE_OFF);

    prep_kernel<<<3329, 256, 0, stream>>>(fm, W1, W2, logits, out, w1r, w2r, cnt, fmT);
    conv_mfma_kernel<<<4096, 256, 0, stream>>>(anchors, fmT, w1r, w2r, b1, logits,
                                               cnt, seg, labels, base_classes, b2, out);
}

// Round 10
// 256.246 us; speedup vs baseline: 4.2451x; 2.3522x over previous
//
#include <hip/hip_runtime.h>

typedef __attribute__((ext_vector_type(8))) short short8;
typedef __attribute__((ext_vector_type(8))) int int8v;
typedef __attribute__((ext_vector_type(16))) float floatx16;
typedef __attribute__((ext_vector_type(4))) unsigned int uint4v;
typedef unsigned short ushort_t;
typedef unsigned int uint_t;
typedef unsigned char uchar_t;

#define NA   256
#define CIN  128
#define HFD  320
#define FMPX (HFD*HFD)
#define IMGD 1280

// ws layout (bytes):
//   [0, 1MB)            logits f32 (NA*1024)
//   [1MB, +294912)      w1b fp8 [cb 2][tap 9][g 4][nt 2][l31*2+kh 64][32 B], scaled x64
//   [+294912, +16384)   w2r bf16 [32 krow][256 oc]
//   [2MB, +13107200)    fmT fp8 [320 y][320 x][128 c]
#define W1B_BYTE_OFF (1u<<20)
#define W2R_BYTE_OFF ((1u<<20) + 9*256*128)
#define FMT_BYTE_OFF (2u<<20)

#define SAPL 5440                 // A sub-plane bytes: 10*34 cells * 16
#define SA_BYTES (4*SAPL)         // 21760
#define PSTR_H 4112               // bytes per oc-octet plane of s_h (8*32*16 + 16 pad)
#define SMEM_BYTES (8*PSTR_H)     // 32896 = max(s_a, s_h)

union V32 { int8v v; uint4v q[2]; };

__device__ __forceinline__ ushort_t f2bf(float v) {
    uint_t u = __float_as_uint(v);
    return (ushort_t)((u + 0x8000u) >> 16);
}
__device__ __forceinline__ uchar_t f2fp8(float v) {
    int r = __builtin_amdgcn_cvt_pk_fp8_f32(v, 0.0f, 0, false);
    return (uchar_t)(r & 0xff);
}

// Fused prep: fm transpose->fp8 channels-last; W1 repack into wave-coalesced B layout (x64 fp8);
// W2 repack (bf16); logits/out zeroing.
// w1b addressing (producer == consumer): cb*147456 + tap*16384 + g*4096 + nt*2048
//                                        + (l31*2+kh)*32 + byte
__global__ __launch_bounds__(256) void prep_kernel(
    const float* __restrict__ fm, const float* __restrict__ W1, const float* __restrict__ W2,
    float* __restrict__ logits, float* __restrict__ out,
    uchar_t* __restrict__ w1b, ushort_t* __restrict__ w2r, uchar_t* __restrict__ fmT)
{
    const int b = blockIdx.x, t = threadIdx.x;
    if (b < 3200) {
        if (b < 1024) logits[b * 256 + t] = 0.0f;
        __shared__ uchar_t s[32 * 144];
        const int y = b / 10, x0b = (b % 10) * 32;
        #pragma unroll
        for (int i = 0; i < 16; ++i) {
            int e = t + 256 * i;
            int c = e >> 5, xo = e & 31;
            s[xo * 144 + c] = f2fp8(fm[(size_t)c * FMPX + y * HFD + x0b + xo]);
        }
        __syncthreads();
        int xo = t >> 3, cg = t & 7;
        uint4v v = *(const uint4v*)&s[xo * 144 + cg * 16];
        *(uint4v*)&fmT[((size_t)(y * HFD + x0b + xo)) * 128 + cg * 16] = v;
    } else if (b < 3328) {
        int e = (b - 3200) * 256 + t;           // 32768 (oc,cin) pairs
        int oc = e >> 7, cin = e & 127;
        int g = oc >> 6, nt = (oc >> 5) & 1, l = oc & 31;
        int cb = cin >> 6, kh = (cin >> 5) & 1, byte = cin & 31;
        int dst = cb * 147456 + g * 4096 + nt * 2048 + (l * 2 + kh) * 32 + byte;
        #pragma unroll
        for (int tap = 0; tap < 9; ++tap)
            w1b[dst + tap * 16384] = f2fp8(W1[(oc * 128 + cin) * 9 + tap] * 64.0f);
    } else {
        #pragma unroll
        for (int i = 0; i < 32; ++i) {
            int e = i * 256 + t;
            int nrow = e >> 8, oc = e & 255;
            w2r[nrow * 256 + oc] = f2bf(nrow < 9 ? W2[oc * 9 + nrow] : 0.0f);
        }
        if (t == 0) out[0] = 0.0f;
    }
}

// Block = (anchor, 8-row quarter, 64-oc group); grid 4096, XCD-swizzled.
// Wave w owns out-rows {2w,2w+1} x 64 oc on mfma_scale 32x32x64 fp8 (unity E8M0=127).
// A in LDS sub-planes [sub 4][10 pr][34 pc][16B]; B from global w1b — repacked so each
// wave's frag-load is a contiguous 2 KB region (lane-stride 32 B, L1-streamable).
// launch_bounds (256,2): VGPR cap 128, no spill (R7: (256,4) => 64-cap => 881 MB scratch).
// LDS 34.3 KB -> 4 blocks/CU = 16 waves/CU.
__global__ __launch_bounds__(256, 2) void conv_mfma_kernel(
    const int* __restrict__ anchors, const uchar_t* __restrict__ fmT,
    const uchar_t* __restrict__ w1b, const ushort_t* __restrict__ w2r,
    const float* __restrict__ b1, float* __restrict__ logits)
{
    const int id  = blockIdx.x;
    const int xcd = id & 7, sid = id >> 3;
    const int n   = xcd * 32 + (sid >> 4);
    const int rem = sid & 15;
    const int q   = rem >> 2;
    const int g   = rem & 3;

    const int t    = threadIdx.x;
    const int w    = t >> 6;
    const int lane = t & 63;
    const int l31  = lane & 31;
    const int kh   = lane >> 5;

    const int x0 = anchors[n * 4 + 0];
    const int y0 = anchors[n * 4 + 2];
    const int r0 = q * 8;

    __shared__ __align__(16) char smem[SMEM_BYTES];   // s_a (21760) union s_h (32896)
    __shared__ float s_log[10 * 32];

    // zero s_a once (pad rows/cols stay zero; real cells overwritten per chunk)
    for (int i = t; i < SA_BYTES / 4; i += 256) ((uint_t*)smem)[i] = 0u;

    floatx16 acc[2][2];
    #pragma unroll
    for (int mt = 0; mt < 2; ++mt)
        #pragma unroll
        for (int nt = 0; nt < 2; ++nt)
            #pragma unroll
            for (int r = 0; r < 16; ++r) acc[mt][nt][r] = 0.0f;

    // per-lane B base: strides match prep (g:4096, nt:2048, lane:32)
    const uchar_t* w1g = w1b + (size_t)(g * 4096) + (l31 * 2 + kh) * 32;

    for (int c = 0; c < 2; ++c) {
        const int cb = c * 64;
        __syncthreads();   // c0: zeros visible; c1: all waves done reading chunk0
        // ---- stage A: 10 rows x 32 cols x 4 subs = 1280 units, exactly 5/thread ----
        #pragma unroll
        for (int j = 0; j < 5; ++j) {
            int u = t + 256 * j;
            int sub = u & 3, cell = u >> 2;
            int col = cell & 31, pr = cell >> 5;
            int cr = r0 + pr - 1;
            if ((unsigned)cr < 32u) {
                uint4v v = *(const uint4v*)&fmT[((size_t)((y0 + cr) * HFD + x0 + col)) * 128 + cb + sub * 16];
                *(uint4v*)(smem + sub * SAPL + (pr * 34 + col + 1) * 16) = v;
            }
        }
        __syncthreads();
        const uchar_t* w1c = w1g + c * 147456;
        // ---- MFMA: per kx cache 4 A-row-frags (ky-shared); B coalesced from global ----
        #pragma unroll
        for (int kx = 0; kx < 3; ++kx) {
            V32 a8[4];
            #pragma unroll
            for (int idx = 0; idx < 4; ++idx) {
                int cell = (2 * w + idx) * 34 + l31 + kx;
                a8[idx].q[0] = *(const uint4v*)(smem + (2 * kh)     * SAPL + cell * 16);
                a8[idx].q[1] = *(const uint4v*)(smem + (2 * kh + 1) * SAPL + cell * 16);
            }
            #pragma unroll
            for (int ky = 0; ky < 3; ++ky) {
                const int tap = ky * 3 + kx;
                V32 b8[2];
                #pragma unroll
                for (int nt = 0; nt < 2; ++nt) {
                    const uchar_t* bp = w1c + tap * 16384 + nt * 2048;
                    b8[nt].q[0] = *(const uint4v*)bp;
                    b8[nt].q[1] = *(const uint4v*)(bp + 16);
                }
                #pragma unroll
                for (int mt = 0; mt < 2; ++mt) {
                    acc[mt][0] = __builtin_amdgcn_mfma_scale_f32_32x32x64_f8f6f4(
                        a8[mt + ky].v, b8[0].v, acc[mt][0], 0, 0, 0, 127, 0, 127);
                    acc[mt][1] = __builtin_amdgcn_mfma_scale_f32_32x32x64_f8f6f4(
                        a8[mt + ky].v, b8[1].v, acc[mt][1], 0, 0, 0, 127, 0, 127);
                }
            }
        }
    }

    // ---- epilogue: h = acc/64 + b1, relu -> s_h (union with s_a) ----
    __syncthreads();
    #pragma unroll
    for (int nt = 0; nt < 2; ++nt) {
        float bias = b1[g * 64 + nt * 32 + l31];
        int plane = nt * 4 + (l31 >> 3);
        #pragma unroll
        for (int mt = 0; mt < 2; ++mt) {
            int lr = 2 * w + mt;
            #pragma unroll
            for (int reg = 0; reg < 16; ++reg) {
                int col = (reg & 3) + 8 * (reg >> 2) + 4 * kh;   // C: m = crop col
                float hv = fmaxf(fmaf(acc[mt][nt][reg], 0.015625f, bias), 0.0f);
                *(ushort_t*)(smem + plane * PSTR_H + ((lr * 32 + col) * 8 + (l31 & 7)) * 2) = f2bf(hv);
            }
        }
    }
    __syncthreads();

    // ---- v_tap = h @ W2^T (bf16, K=64 oc over 4 x K16) ----
    floatx16 vacc[2];
    #pragma unroll
    for (int mt = 0; mt < 2; ++mt)
        #pragma unroll
        for (int r = 0; r < 16; ++r) vacc[mt][r] = 0.0f;
    #pragma unroll
    for (int ks = 0; ks < 4; ++ks) {
        short8 bw = *(const short8*)&w2r[l31 * 256 + g * 64 + ks * 16 + kh * 8];
        #pragma unroll
        for (int mt = 0; mt < 2; ++mt) {
            short8 ah = *(const short8*)(smem + (ks * 2 + kh) * PSTR_H + ((2 * w + mt) * 32 + l31) * 16);
            vacc[mt] = __builtin_amdgcn_mfma_f32_32x32x16_bf16(ah, bw, vacc[mt], 0, 0, 0);
        }
    }

    // ---- scatter v_tap into 10x32 tile, then global atomics ----
    __syncthreads();
    for (int i = t; i < 10 * 32; i += 256) s_log[i] = 0.0f;
    __syncthreads();
    if (l31 < 9) {
        int ky = l31 / 3, kx = l31 - ky * 3;
        #pragma unroll
        for (int mt = 0; mt < 2; ++mt) {
            int outr = 2 * w + mt + 2 - ky;       // tile row; R = r0 + outr - 1
            #pragma unroll
            for (int reg = 0; reg < 16; ++reg) {
                int col  = (reg & 3) + 8 * (reg >> 2) + 4 * kh;
                int outc = col + 1 - kx;
                if (outc >= 0 && outc < 32)
                    atomicAdd(&s_log[outr * 32 + outc], vacc[mt][reg]);
            }
        }
    }
    __syncthreads();
    for (int i = t; i < 10 * 32; i += 256) {
        int outr = i >> 5, outc = i & 31;
        int R = r0 + outr - 1;
        if ((unsigned)R < 32u)
            atomicAdd(&logits[n * 1024 + R * 32 + outc], s_log[i]);
    }
}

__global__ __launch_bounds__(256) void bce_reduce_kernel(
    const float* __restrict__ logits, const int* __restrict__ seg,
    const int* __restrict__ anchors, const int* __restrict__ labels,
    const int* __restrict__ base_classes, const float* __restrict__ b2,
    float* __restrict__ out)
{
    const int n = blockIdx.x;
    const int t = threadIdx.x;
    const int y0 = anchors[n * 4 + 2];
    const int x0 = anchors[n * 4 + 0];
    const int tgt_cls = base_classes[labels[n]];
    const float bias2 = b2[0];

    float lsum = 0.0f;
    #pragma unroll
    for (int r = 0; r < 4; ++r) {
        int p = t + r * 256;
        int i = p >> 5, j = p & 31;
        float l = logits[n * 1024 + p] + bias2;
        int sv = seg[(size_t)(4 * (y0 + i)) * IMGD + 4 * (x0 + j)];
        float tgt = (sv == tgt_cls) ? 1.0f : 0.0f;
        lsum += fmaxf(l, 0.0f) - l * tgt + log1pf(expf(-fabsf(l)));
    }
    #pragma unroll
    for (int off = 32; off > 0; off >>= 1) lsum += __shfl_down(lsum, off, 64);
    __shared__ float s[4];
    if ((t & 63) == 0) s[t >> 6] = lsum;
    __syncthreads();
    if (t == 0) {
        float tot = s[0] + s[1] + s[2] + s[3];
        const float scale = 1.0f / (1024.0f * (256.0f + 1e-10f));
        atomicAdd(out, tot * scale);
    }
}

extern "C" void kernel_launch(void* const* d_in, const int* in_sizes, int n_in,
                              void* d_out, int out_size, void* d_ws, size_t ws_size,
                              hipStream_t stream) {
    const float* fm           = (const float*)d_in[0];
    const int*   seg          = (const int*)d_in[1];
    const int*   anchors      = (const int*)d_in[2];
    const int*   labels       = (const int*)d_in[3];
    const int*   base_classes = (const int*)d_in[4];
    const float* W1           = (const float*)d_in[5];
    const float* b1           = (const float*)d_in[6];
    const float* W2           = (const float*)d_in[7];
    const float* b2           = (const float*)d_in[8];
    float* out = (float*)d_out;

    float*    logits = (float*)d_ws;
    uchar_t*  w1b    = (uchar_t*)((char*)d_ws + W1B_BYTE_OFF);
    ushort_t* w2r    = (ushort_t*)((char*)d_ws + W2R_BYTE_OFF);
    uchar_t*  fmT    = (uchar_t*)((char*)d_ws + FMT_BYTE_OFF);

    prep_kernel<<<3329, 256, 0, stream>>>(fm, W1, W2, logits, out, w1b, w2r, fmT);
    conv_mfma_kernel<<<4096, 256, 0, stream>>>(anchors, fmT, w1b, w2r, b1, logits);
    bce_reduce_kernel<<<NA, 256, 0, stream>>>(logits, seg, anchors, labels, base_classes, b2, out);
}